// Round 3
// baseline (152.940 us; speedup 1.0000x reference)
//
#include <hip/hip_runtime.h>
#include <stdint.h>

// ---------------------------------------------------------------------------
// MultiAttentionHead: B=4 S=1024 E=1024 H=16 D=64, fp32 in/out.
// R14: k_attn COUNTED VMCNT (T4). The per-iter __syncthreads drained
// vmcnt(0) -- killing the dbuf prefetch every iteration (DMA latency
// ~300-600cy not hidden by ~500-700cy compute). Now raw s_barriers with
// derived waits: per iter issue K(2)+V(2) for t+1; barrier#1 (P handoff)
// waits lgkmcnt(0)+vmcnt(4) (V_t drained, t+1 stays in flight); barrier#2
// (end) waits vmcnt(2) (K_{t+1} drained for next QK, V_{t+1} in flight).
// Last iter: vmcnt(0) at #1 (nothing new issued). Reads of cur/P drain via
// MFMA data-deps before barriers; t+1 DMA issued after end-barrier of t-1
// separates WAR. No arithmetic change -> bit-identical output.
// R13: k_proj dead-row skip (z=0/1 blocks with sbase>=len early-return).
// R12: k_attn swapped QK^T (S^T=K*Q), K as A-operand (2 ds_read vs 8),
// persistent Q B-frags, packed ds_write_b64 P.
// Carried: R1 XOR swizzle (0 conflicts), R4 static softmax, R7 dbuf,
// R8 LDS epilogue + direct V^T, R10 all-fp16, R11 batch-balance remap.
// R9 post-mortem: k_proj BK=32 dbuf regressed -> keeps BK=64 2-barrier.
// ---------------------------------------------------------------------------

using u16     = unsigned short;
using half8   = __attribute__((ext_vector_type(8))) _Float16;
using floatx4 = __attribute__((ext_vector_type(4))) float;

#define MFMA16(a, b, c) __builtin_amdgcn_mfma_f32_16x16x32_f16(a, b, c, 0, 0, 0)

__device__ __forceinline__ u16 f2h(float f) {  // f32 -> f16 bits (RTN)
  _Float16 h = (_Float16)f; u16 u; __builtin_memcpy(&u, &h, 2); return u;
}

// async global->LDS DMA, 16B per lane. LDS dest must be wave-uniform base +
// lane*16 (no per-lane scatter) -- so bank swizzles permute the GLOBAL src.
__device__ __forceinline__ void async_cp16(void* lds, const void* g) {
  __builtin_amdgcn_global_load_lds(
      (__attribute__((address_space(1))) uint32_t*)(uintptr_t)g,
      (__attribute__((address_space(3))) uint32_t*)(uint32_t)(uintptr_t)lds,
      16, 0, 0);
}

// ---------------------------------------------------------------------------
// 1) prep (fused): blocks [0,4096): x -> f16 (block 0 zeroes vsum);
//    blocks [4096,7168): transpose W -> WT[n][k] f16.
// ---------------------------------------------------------------------------
__global__ void k_prep(const float* __restrict__ x, u16* __restrict__ xh,
                       const float* __restrict__ w0, const float* __restrict__ w1,
                       const float* __restrict__ w2,
                       u16* __restrict__ o0, u16* __restrict__ o1,
                       u16* __restrict__ o2, float* __restrict__ vsum) {
  __shared__ float t[32][33];
  const int bx = blockIdx.x;
  if (bx < 4096) {
    int i = (bx * 256 + threadIdx.x) * 4;
    float4 v = *(const float4*)(x + i);
    ushort4 hv;
    hv.x = f2h(v.x);
    hv.y = f2h(v.y);
    hv.z = f2h(v.z);
    hv.w = f2h(v.w);
    *(ushort4*)(xh + i) = hv;
    if (bx == 0) {  // zero vsum (4096 floats) for k_proj's atomics
      float4 z = {0.f, 0.f, 0.f, 0.f};
#pragma unroll
      for (int e = 0; e < 4; e++) ((float4*)vsum)[threadIdx.x * 4 + e] = z;
    }
    return;
  }
  const int id = bx - 4096;                 // 0..3071
  const int z = id >> 10, rem = id & 1023;
  const float* W = z == 0 ? w0 : (z == 1 ? w1 : w2);
  u16* oh = z == 0 ? o0 : (z == 1 ? o1 : o2);
  const int kb = (rem & 31) * 32, nb = (rem >> 5) * 32;
  const int tx = threadIdx.x & 31, ty = threadIdx.x >> 5;
  for (int r = ty; r < 32; r += 8) t[r][tx] = W[(kb + r) * 1024 + nb + tx];
  __syncthreads();
  for (int r = ty; r < 32; r += 8)
    oh[(nb + r) * 1024 + kb + tx] = f2h(t[tx][r]);
}

// ---------------------------------------------------------------------------
// 2) projection GEMM: C[4096][1024] = xh @ Wh + b, fp16 single pass,
//    128x128 tile, BK=64, 2-barrier K-loop (R9: dbuf regresses here).
//    LDS 32 KB staging / 34.8 KB epilogue tile -> 4 blocks/CU. Epilogue
//    stages C through LDS ([128][136]) for 16B stores. z=0/1 -> q/k f16 in
//    [B][H][S][D] (q pre-scaled by 0.125*log2e); z=2 -> V^T f16 + vsum.
//    R13: z=0/1 blocks whose 128 s-rows are all >= len[b] early-return.
// ---------------------------------------------------------------------------
__launch_bounds__(256, 4)
__global__ void k_proj(const u16* __restrict__ xh,
                       const u16* __restrict__ wqT, const u16* __restrict__ wkT,
                       const u16* __restrict__ wvT,
                       const float* __restrict__ bq, const float* __restrict__ bk,
                       const float* __restrict__ bv,
                       const int* __restrict__ elen,
                       u16* __restrict__ qh, u16* __restrict__ kh,
                       u16* __restrict__ vth, float* __restrict__ vsum) {
  __shared__ u16 Sm[17408];  // K-loop: A@0, B@8192 ([128][64] f16 = 16 KB ea);
                             // epilogue: C tile [128][136] (34816 B)
  const int z = blockIdx.z;
  const int m0 = blockIdx.x * 128, n0 = blockIdx.y * 128;
  // R13 dead-row skip: Q/K rows >= len[batch] are never consumed downstream.
  if (z != 2 && (m0 & 1023) >= elen[m0 >> 10]) return;  // block-uniform

  const u16* wT = z == 0 ? wqT : (z == 1 ? wkT : wvT);
  const float* bias = z == 0 ? bq : (z == 1 ? bk : bv);
  u16* oh = z == 0 ? qh : (z == 1 ? kh : vth);
  const float oscale = (z == 0) ? 0.18033688011112042f : 1.0f;  // 0.125*log2(e)

  const int tid = threadIdx.x, l = tid & 63, w = tid >> 6;
  const int quad = l >> 4, col = l & 15;
  const int wm = (w & 1) * 64, wn = (w >> 1) * 64;

  const int row0 = tid >> 3, ch = tid & 7;
  const int sc8 = (ch ^ (row0 & 7)) * 8;
  int gofs[4], lofs[4];
#pragma unroll
  for (int p = 0; p < 4; p++) {
    gofs[p] = (row0 + 32 * p) * 1024 + sc8;
    lofs[p] = (tid + p * 256) * 8;
  }

  const u16* Ag = xh + m0 * 1024;
  const u16* Bg = wT + n0 * 1024;

  int ar[2][4], br[2][4];
#pragma unroll
  for (int ks = 0; ks < 2; ks++) {
#pragma unroll
    for (int i = 0; i < 4; i++) {
      int r = wm + i * 16 + col;
      ar[ks][i] = r * 64 + (((ks * 4 + quad) ^ (r & 7)) * 8);
    }
#pragma unroll
    for (int j = 0; j < 4; j++) {
      int r = wn + j * 16 + col;
      br[ks][j] = r * 64 + (((ks * 4 + quad) ^ (r & 7)) * 8);
    }
  }

  floatx4 zero4 = {0.f, 0.f, 0.f, 0.f};
  floatx4 acc[4][4];
#pragma unroll
  for (int i = 0; i < 4; i++)
#pragma unroll
    for (int j = 0; j < 4; j++) acc[i][j] = zero4;

  for (int k0 = 0; k0 < 1024; k0 += 64) {
    __syncthreads();  // previous compute done before LDS overwrite
#pragma unroll
    for (int p = 0; p < 4; p++) async_cp16(Sm + lofs[p], Ag + gofs[p] + k0);
#pragma unroll
    for (int p = 0; p < 4; p++)
      async_cp16(Sm + 8192 + lofs[p], Bg + gofs[p] + k0);
    __syncthreads();  // DMA drained

#pragma unroll
    for (int ks = 0; ks < 2; ks++) {
      half8 fa[4], fb[4];
#pragma unroll
      for (int i = 0; i < 4; i++) fa[i] = *(const half8*)(Sm + ar[ks][i]);
#pragma unroll
      for (int j = 0; j < 4; j++)
        fb[j] = *(const half8*)(Sm + 8192 + br[ks][j]);
#pragma unroll
      for (int i = 0; i < 4; i++)
#pragma unroll
        for (int j = 0; j < 4; j++) acc[i][j] = MFMA16(fa[i], fb[j], acc[i][j]);
    }
  }

  // ---- epilogue: stage C tile in LDS ([128][136]) for coalesced stores ----
  const int bidx = m0 >> 10;     // batch index
  const int sbase = m0 & 1023;
  __syncthreads();  // all K-loop LDS reads done before overwrite

#pragma unroll
  for (int j = 0; j < 4; j++) {
    int nloc = wn + j * 16 + col;
    float bb = bias[n0 + nloc];
#pragma unroll
    for (int i = 0; i < 4; i++)
#pragma unroll
      for (int r = 0; r < 4; r++) {
        int mloc = wm + i * 16 + quad * 4 + r;
        Sm[mloc * 136 + nloc] = f2h((acc[i][j][r] + bb) * oscale);
      }
  }
  __syncthreads();

  if (z != 2) {
    // q/k: [bh][s][64] -- row-contiguous 16B chunks
#pragma unroll
    for (int k = 0; k < 8; k++) {
      int c = tid + k * 256;
      int mloc = c >> 4, n = (c & 15) * 8;
      int hh = (n0 + n) >> 6, d = (n0 + n) & 63;
      half8 vv = *(const half8*)(Sm + mloc * 136 + n);
      *(half8*)(oh + ((bidx * 16 + hh) * 1024 + sbase + mloc) * 64 + d) = vv;
    }
  } else {
    // V^T: [bh][d][1024] -- transposed read, s-contiguous 16B stores
#pragma unroll
    for (int k = 0; k < 8; k++) {
      int c = tid + k * 256;
      int nloc = c & 127, s0 = (c >> 7) * 8;
      int hh = (n0 + nloc) >> 6, d = (n0 + nloc) & 63;
      u16 tmp[8];
#pragma unroll
      for (int e = 0; e < 8; e++) tmp[e] = Sm[(s0 + e) * 136 + nloc];
      *(half8*)(vth + ((bidx * 16 + hh) * 64 + d) * 1024 + sbase + s0) =
          *(half8*)tmp;
    }
    // vsum partials from fp32 acc: vsum[bh*64+d] += sum over this block's s
#pragma unroll
    for (int j = 0; j < 4; j++) {
      int nloc = wn + j * 16 + col;
      float bb = bias[n0 + nloc];
      float part = 16.0f * bb;
#pragma unroll
      for (int i = 0; i < 4; i++)
#pragma unroll
        for (int r = 0; r < 4; r++) part += acc[i][j][r];
      part += __shfl_xor(part, 16, 64);  // reduce across quads (same n)
      part += __shfl_xor(part, 32, 64);
      if (quad == 0) {
        int hh = (n0 + nloc) >> 6, d = (n0 + nloc) & 63;
        unsafeAtomicAdd(vsum + (bidx * 16 + hh) * 64 + d, part);
      }
    }
  }
}

// ---------------------------------------------------------------------------
// Swizzled 64x64 f16 tile stage (global -> LDS via DMA).
// ---------------------------------------------------------------------------
__device__ __forceinline__ void stage64(u16* lds, const u16* g, int row_stride,
                                        int tid) {
#pragma unroll
  for (int p = 0; p < 2; p++) {
    int slot = (p * 256 + tid) * 8;  // element index; *2 = bytes
    int row = slot >> 6;
    int gp = (slot >> 3) & 7;
    int gl = gp ^ (row & 7);
    async_cp16(lds + slot, g + row * row_stride + gl * 8);
  }
}

// ---------------------------------------------------------------------------
// 3) flash attention, fp16, static softmax, double-buffered staging.
//    R14 loop structure (per tile t), counted vmcnt -- never drain to 0
//    mid-loop (T4). Per wave, per iter: issue K_{t+1}(2 loads) then
//    V_{t+1}(2 loads). Waits:
//      barrier#1 (P handoff):  lgkmcnt(0) + vmcnt(4)  [V_t done]
//      barrier#2 (iter end):   vmcnt(2)               [K_{t+1} done]
//    Last iter issues nothing: vmcnt(0) at #1, plain barrier at #2.
//    cur-buffer reads drain via MFMA data-deps before barriers; t+1 DMA is
//    issued after end-barrier of t-1, separating the WAR on buf[(t+1)&1].
// ---------------------------------------------------------------------------
__launch_bounds__(256)
__global__ void k_attn(const u16* __restrict__ qh_g,
                       const u16* __restrict__ kh_g,
                       const u16* __restrict__ vth_g,
                       const float* __restrict__ vsum, const int* __restrict__ elen,
                       float* __restrict__ out) {
  __shared__ u16 QP[4096];       // [64][64] swizzled: Q, then P (aliased)
  __shared__ u16 Bufs[2][8192];  // per buf: K@0, VT@4096 ([64][64] swizzled)
  const int tid = threadIdx.x, l = tid & 63, w = tid >> 6;
  const int quad = l >> 4, col = l & 15;
  // ---- R11 balance remap (bijective): each CU's {id, id+256, id+512,
  //      id+768} resident set cycles through all 4 batches ----
  const int id = blockIdx.x;
  const int b = (id + (id >> 8)) & 3;
  const int h = (id >> 2) & 15;
  const int bh = b * 16 + h;
  const int q0 = ((id >> 6) & 15) * 64;
  const int len = elen[b];

  if (q0 >= len) {  // fully-invalid tile: uniform attention over ALL t (ref)
    float val = vsum[bh * 64 + l] * (1.0f / 1024.0f);
    float* op = out + (b * 1024 + q0) * 1024 + h * 64 + l;
    for (int r = w; r < 64; r += 4) op[r * 1024] = val;
    return;
  }

  const u16* kh_b  = kh_g + bh * 65536;
  const u16* vth_b = vth_g + bh * 65536;

  // prologue: stage Q + tile 0, full drain
  stage64(QP, qh_g + (bh * 1024 + q0) * 64, 64, tid);
  stage64(Bufs[0], kh_b, 64, tid);
  stage64(Bufs[0] + 4096, vth_b, 1024, tid);
  __syncthreads();

  // persistent Q as B-operand fragments: qf[jq][ks], row = jq*16 + col
  half8 qf[4][2];
#pragma unroll
  for (int jq = 0; jq < 4; jq++) {
    int qrow = jq * 16 + col;
#pragma unroll
    for (int ks = 0; ks < 2; ks++)
      qf[jq][ks] = *(const half8*)(QP + qrow * 64 +
                                   (((ks * 4 + quad) ^ (qrow & 7)) * 8));
  }

  // K A-frag / P A-frag offsets (same formula: row = w*16 + col)
  int ko[2];
#pragma unroll
  for (int ks = 0; ks < 2; ks++) {
    int r = w * 16 + col;
    ko[ks] = r * 64 + (((ks * 4 + quad) ^ (r & 7)) * 8);
  }
  // V B-frag offsets (n = j*16 + col)
  int kvo[2][4];
#pragma unroll
  for (int ks = 0; ks < 2; ks++)
#pragma unroll
    for (int j = 0; j < 4; j++) {
      int n = j * 16 + col;
      kvo[ks][j] = n * 64 + (((ks * 4 + quad) ^ (n & 7)) * 8);
    }
  // packed P write offsets: row = jq*16+col, t-chunk = w*2 + (quad>>1),
  // 8B slot at (quad&1)*4 elems within the chunk
  int p_wr[4];
  {
    int chv = w * 2 + (quad >> 1);
#pragma unroll
    for (int jq = 0; jq < 4; jq++) {
      int row = jq * 16 + col;
      p_wr[jq] = row * 64 + ((chv ^ (row & 7)) * 8) + (quad & 1) * 4;
    }
  }

  floatx4 zero4 = {0.f, 0.f, 0.f, 0.f};
  floatx4 O[4];
  float lp[4];  // per-thread l partials: lp[jq] over this thread's t-slice
#pragma unroll
  for (int j = 0; j < 4; j++) O[j] = zero4;
#pragma unroll
  for (int jq = 0; jq < 4; jq++) lp[jq] = 0.f;

  const int ntt = (len + 63) >> 6;
  for (int tt = 0; tt < ntt; ++tt) {
    const int t0 = tt * 64;
    u16* cur = Bufs[tt & 1];
    const bool pf = (tt + 1 < ntt);  // wave-uniform
    if (pf) {  // issue order matters for the counted waits: K(2) then V(2)
      u16* nxt = Bufs[(tt + 1) & 1];
      const int t1 = t0 + 64;
      stage64(nxt, kh_b + t1 * 64, 64, tid);         // K_{t+1}
      stage64(nxt + 4096, vth_b + t1, 1024, tid);    // V_{t+1}
    }

    // ---- S^T = K Q (q carries 0.125*log2e); sc[jq][r]:
    //      q = jq*16 + col, t = t0 + w*16 + quad*4 + r ----
    floatx4 sc[4];
#pragma unroll
    for (int jq = 0; jq < 4; jq++) sc[jq] = zero4;
#pragma unroll
    for (int ks = 0; ks < 2; ks++) {
      half8 kf = *(const half8*)(cur + ko[ks]);
#pragma unroll
      for (int jq = 0; jq < 4; jq++) sc[jq] = MFMA16(kf, qf[jq][ks], sc[jq]);
    }

    if (t0 + 64 > len) {  // only the last partial tile masks (t-cols >= len)
#pragma unroll
      for (int r = 0; r < 4; r++) {
        bool inv = (t0 + w * 16 + quad * 4 + r) >= len;
#pragma unroll
        for (int jq = 0; jq < 4; jq++)
          if (inv) sc[jq][r] = -3e38f;  // exp2 -> 0 (assignment kills NaN)
      }
    }

    // ---- static softmax: p = exp2(score), f16 RTN, packed b64 writes ----
#pragma unroll
    for (int jq = 0; jq < 4; jq++) {
      float e0 = __builtin_exp2f(sc[jq][0]);
      float e1 = __builtin_exp2f(sc[jq][1]);
      float e2 = __builtin_exp2f(sc[jq][2]);
      float e3 = __builtin_exp2f(sc[jq][3]);
      lp[jq] += (e0 + e1) + (e2 + e3);
      uint2 pk;
      pk.x = (uint32_t)f2h(e0) | ((uint32_t)f2h(e1) << 16);
      pk.y = (uint32_t)f2h(e2) | ((uint32_t)f2h(e3) << 16);
      *(uint2*)(QP + p_wr[jq]) = pk;  // 4 consecutive t -> one ds_write_b64
    }

    // ---- barrier #1: P handoff + V_t visibility. vmcnt(4) keeps the four
    //      t+1 loads in flight; lgkmcnt(0) publishes P writes. ----
    if (pf) {
      asm volatile("s_waitcnt lgkmcnt(0) vmcnt(4)" ::: "memory");
    } else {
      asm volatile("s_waitcnt lgkmcnt(0) vmcnt(0)" ::: "memory");
    }
    __builtin_amdgcn_s_barrier();
    __builtin_amdgcn_sched_barrier(0);

    // ---- O += P * V ----
#pragma unroll
    for (int ks = 0; ks < 2; ks++) {
      half8 pa = *(const half8*)(QP + ko[ks]);
#pragma unroll
      for (int j = 0; j < 4; j++) {
        half8 vb = *(const half8*)(cur + 4096 + kvo[ks][j]);
        O[j] = MFMA16(pa, vb, O[j]);
      }
    }

    // ---- barrier #2: iter end. vmcnt(2) = K_{t+1} landed (next QK safe);
    //      V_{t+1}'s 2 loads stay in flight across the barrier. ----
    if (pf) {
      asm volatile("s_waitcnt vmcnt(2)" ::: "memory");
    }
    __builtin_amdgcn_s_barrier();
    __builtin_amdgcn_sched_barrier(0);
  }

  // ---- epilogue: cross-wave l reduction through (now free) Bufs ----
  float* lred = (float*)Bufs;  // [4 waves][64 q] partials
#pragma unroll
  for (int jq = 0; jq < 4; jq++) {
    float v = lp[jq];
    v += __shfl_xor(v, 16, 64);  // sum over quads (wave's 16-t slice, all tt)
    v += __shfl_xor(v, 32, 64);
    lp[jq] = v;
  }
  if (quad == 0) {
#pragma unroll
    for (int jq = 0; jq < 4; jq++) lred[w * 64 + jq * 16 + col] = lp[jq];
  }
  __syncthreads();

#pragma unroll
  for (int r = 0; r < 4; r++) {
    int qloc = w * 16 + quad * 4 + r;
    int s = q0 + qloc;
    float lr = (lred[qloc] + lred[64 + qloc]) +
               (lred[128 + qloc] + lred[192 + qloc]);
    float invl = 1.0f / lr;
    bool valid = (s < len);
#pragma unroll
    for (int j = 0; j < 4; j++) {
      int d = j * 16 + col;
      float val = valid ? O[j][r] * invl : vsum[bh * 64 + d] * (1.0f / 1024.0f);
      out[(b * 1024 + s) * 1024 + h * 64 + d] = val;
    }
  }
}

// ---------------------------------------------------------------------------
// launch
// ---------------------------------------------------------------------------
extern "C" void kernel_launch(void* const* d_in, const int* in_sizes, int n_in,
                              void* d_out, int out_size, void* d_ws, size_t ws_size,
                              hipStream_t stream) {
  (void)in_sizes; (void)n_in; (void)out_size; (void)ws_size;
  const float* x  = (const float*)d_in[0];
  const float* Wq = (const float*)d_in[1];
  const float* bq = (const float*)d_in[2];
  const float* Wk = (const float*)d_in[3];
  const float* bk = (const float*)d_in[4];
  const float* Wv = (const float*)d_in[5];
  const float* bv = (const float*)d_in[6];
  const int* elen = (const int*)d_in[7];
  float* out = (float*)d_out;

  char* ws = (char*)d_ws;
  const size_t MB = 1024 * 1024;
  u16* xh  = (u16*)(ws + 0 * MB);
  u16* wqT = (u16*)(ws + 8 * MB);
  u16* wkT = (u16*)(ws + 10 * MB);
  u16* wvT = (u16*)(ws + 12 * MB);
  u16* qh  = (u16*)(ws + 14 * MB);
  u16* kh  = (u16*)(ws + 22 * MB);
  u16* vth = (u16*)(ws + 30 * MB);
  float* vsum = (float*)(ws + 38 * MB);  // 4096 floats

  k_prep<<<7168, 256, 0, stream>>>(x, xh, Wq, Wk, Wv, wqT, wkT, wvT, vsum);
  k_proj<<<dim3(32, 8, 3), 256, 0, stream>>>(xh, wqT, wkT, wvT, bq, bk, bv,
                                             elen, qh, kh, vth, vsum);
  k_attn<<<1024, 256, 0, stream>>>(qh, kh, vth, vsum, elen, out);
}

// Round 4
// 147.276 us; speedup vs baseline: 1.0385x; 1.0385x over previous
//
#include <hip/hip_runtime.h>
#include <stdint.h>

// ---------------------------------------------------------------------------
// MultiAttentionHead: B=4 S=1024 E=1024 H=16 D=64, fp32 in/out.
// R15: k_attn QBLK=128 (512 thr, 8 waves), R14 sync REVERTED to R13's
// __syncthreads loop (R14 counted-vmcnt regressed +3.7us: sched_barrier
// pinning on a 2-barrier loop = the documented m131/m141 null/regression).
// Each block now covers 128 q-rows -> K/V staged ONCE per 128 q (L2->LDS
// traffic and barrier-pairs halved per unit work). QK: wave w = (t-block
// w&3, q-half w>>2), 8 MFMA/wave; PV: wave w = q-block w, 8 MFMA/wave.
// Per-wave mix unchanged (16 LDS / 16 MFMA / 16 exp2 per iter). LDS 48KB,
// grid 512 = 2 blk/CU x 8 waves = 16 waves/CU (same as before). One-time
// barrier after qf loads closes the Q-read/P-write alias race.
// R13: k_proj dead-row skip (z=0/1 blocks with sbase>=len early-return).
// R12: swapped QK^T (S^T=K*Q), K as A-operand, persistent Q B-frags,
// packed ds_write_b64 P, mid-iter lgkmcnt-only barrier.
// Carried: R1 XOR swizzle (0 conflicts), R4 static softmax, R7 dbuf,
// R8 LDS epilogue + direct V^T, R10 all-fp16, R11 batch-balance remap.
// R9/R14 post-mortems: 2-barrier loops reject dbuf/counted-vmcnt tweaks.
// ---------------------------------------------------------------------------

using u16     = unsigned short;
using half8   = __attribute__((ext_vector_type(8))) _Float16;
using floatx4 = __attribute__((ext_vector_type(4))) float;

#define MFMA16(a, b, c) __builtin_amdgcn_mfma_f32_16x16x32_f16(a, b, c, 0, 0, 0)

__device__ __forceinline__ u16 f2h(float f) {  // f32 -> f16 bits (RTN)
  _Float16 h = (_Float16)f; u16 u; __builtin_memcpy(&u, &h, 2); return u;
}

// async global->LDS DMA, 16B per lane. LDS dest must be wave-uniform base +
// lane*16 (no per-lane scatter) -- so bank swizzles permute the GLOBAL src.
__device__ __forceinline__ void async_cp16(void* lds, const void* g) {
  __builtin_amdgcn_global_load_lds(
      (__attribute__((address_space(1))) uint32_t*)(uintptr_t)g,
      (__attribute__((address_space(3))) uint32_t*)(uint32_t)(uintptr_t)lds,
      16, 0, 0);
}

// ---------------------------------------------------------------------------
// 1) prep (fused): blocks [0,4096): x -> f16 (block 0 zeroes vsum);
//    blocks [4096,7168): transpose W -> WT[n][k] f16.
// ---------------------------------------------------------------------------
__global__ void k_prep(const float* __restrict__ x, u16* __restrict__ xh,
                       const float* __restrict__ w0, const float* __restrict__ w1,
                       const float* __restrict__ w2,
                       u16* __restrict__ o0, u16* __restrict__ o1,
                       u16* __restrict__ o2, float* __restrict__ vsum) {
  __shared__ float t[32][33];
  const int bx = blockIdx.x;
  if (bx < 4096) {
    int i = (bx * 256 + threadIdx.x) * 4;
    float4 v = *(const float4*)(x + i);
    ushort4 hv;
    hv.x = f2h(v.x);
    hv.y = f2h(v.y);
    hv.z = f2h(v.z);
    hv.w = f2h(v.w);
    *(ushort4*)(xh + i) = hv;
    if (bx == 0) {  // zero vsum (4096 floats) for k_proj's atomics
      float4 z = {0.f, 0.f, 0.f, 0.f};
#pragma unroll
      for (int e = 0; e < 4; e++) ((float4*)vsum)[threadIdx.x * 4 + e] = z;
    }
    return;
  }
  const int id = bx - 4096;                 // 0..3071
  const int z = id >> 10, rem = id & 1023;
  const float* W = z == 0 ? w0 : (z == 1 ? w1 : w2);
  u16* oh = z == 0 ? o0 : (z == 1 ? o1 : o2);
  const int kb = (rem & 31) * 32, nb = (rem >> 5) * 32;
  const int tx = threadIdx.x & 31, ty = threadIdx.x >> 5;
  for (int r = ty; r < 32; r += 8) t[r][tx] = W[(kb + r) * 1024 + nb + tx];
  __syncthreads();
  for (int r = ty; r < 32; r += 8)
    oh[(nb + r) * 1024 + kb + tx] = f2h(t[tx][r]);
}

// ---------------------------------------------------------------------------
// 2) projection GEMM: C[4096][1024] = xh @ Wh + b, fp16 single pass,
//    128x128 tile, BK=64, 2-barrier K-loop (R9: dbuf regresses here).
//    LDS 32 KB staging / 34.8 KB epilogue tile -> 4 blocks/CU. Epilogue
//    stages C through LDS ([128][136]) for 16B stores. z=0/1 -> q/k f16 in
//    [B][H][S][D] (q pre-scaled by 0.125*log2e); z=2 -> V^T f16 + vsum.
//    R13: z=0/1 blocks whose 128 s-rows are all >= len[b] early-return.
// ---------------------------------------------------------------------------
__launch_bounds__(256, 4)
__global__ void k_proj(const u16* __restrict__ xh,
                       const u16* __restrict__ wqT, const u16* __restrict__ wkT,
                       const u16* __restrict__ wvT,
                       const float* __restrict__ bq, const float* __restrict__ bk,
                       const float* __restrict__ bv,
                       const int* __restrict__ elen,
                       u16* __restrict__ qh, u16* __restrict__ kh,
                       u16* __restrict__ vth, float* __restrict__ vsum) {
  __shared__ u16 Sm[17408];  // K-loop: A@0, B@8192 ([128][64] f16 = 16 KB ea);
                             // epilogue: C tile [128][136] (34816 B)
  const int z = blockIdx.z;
  const int m0 = blockIdx.x * 128, n0 = blockIdx.y * 128;
  // R13 dead-row skip: Q/K rows >= len[batch] are never consumed downstream.
  if (z != 2 && (m0 & 1023) >= elen[m0 >> 10]) return;  // block-uniform

  const u16* wT = z == 0 ? wqT : (z == 1 ? wkT : wvT);
  const float* bias = z == 0 ? bq : (z == 1 ? bk : bv);
  u16* oh = z == 0 ? qh : (z == 1 ? kh : vth);
  const float oscale = (z == 0) ? 0.18033688011112042f : 1.0f;  // 0.125*log2(e)

  const int tid = threadIdx.x, l = tid & 63, w = tid >> 6;
  const int quad = l >> 4, col = l & 15;
  const int wm = (w & 1) * 64, wn = (w >> 1) * 64;

  const int row0 = tid >> 3, ch = tid & 7;
  const int sc8 = (ch ^ (row0 & 7)) * 8;
  int gofs[4], lofs[4];
#pragma unroll
  for (int p = 0; p < 4; p++) {
    gofs[p] = (row0 + 32 * p) * 1024 + sc8;
    lofs[p] = (tid + p * 256) * 8;
  }

  const u16* Ag = xh + m0 * 1024;
  const u16* Bg = wT + n0 * 1024;

  int ar[2][4], br[2][4];
#pragma unroll
  for (int ks = 0; ks < 2; ks++) {
#pragma unroll
    for (int i = 0; i < 4; i++) {
      int r = wm + i * 16 + col;
      ar[ks][i] = r * 64 + (((ks * 4 + quad) ^ (r & 7)) * 8);
    }
#pragma unroll
    for (int j = 0; j < 4; j++) {
      int r = wn + j * 16 + col;
      br[ks][j] = r * 64 + (((ks * 4 + quad) ^ (r & 7)) * 8);
    }
  }

  floatx4 zero4 = {0.f, 0.f, 0.f, 0.f};
  floatx4 acc[4][4];
#pragma unroll
  for (int i = 0; i < 4; i++)
#pragma unroll
    for (int j = 0; j < 4; j++) acc[i][j] = zero4;

  for (int k0 = 0; k0 < 1024; k0 += 64) {
    __syncthreads();  // previous compute done before LDS overwrite
#pragma unroll
    for (int p = 0; p < 4; p++) async_cp16(Sm + lofs[p], Ag + gofs[p] + k0);
#pragma unroll
    for (int p = 0; p < 4; p++)
      async_cp16(Sm + 8192 + lofs[p], Bg + gofs[p] + k0);
    __syncthreads();  // DMA drained

#pragma unroll
    for (int ks = 0; ks < 2; ks++) {
      half8 fa[4], fb[4];
#pragma unroll
      for (int i = 0; i < 4; i++) fa[i] = *(const half8*)(Sm + ar[ks][i]);
#pragma unroll
      for (int j = 0; j < 4; j++)
        fb[j] = *(const half8*)(Sm + 8192 + br[ks][j]);
#pragma unroll
      for (int i = 0; i < 4; i++)
#pragma unroll
        for (int j = 0; j < 4; j++) acc[i][j] = MFMA16(fa[i], fb[j], acc[i][j]);
    }
  }

  // ---- epilogue: stage C tile in LDS ([128][136]) for coalesced stores ----
  const int bidx = m0 >> 10;     // batch index
  const int sbase = m0 & 1023;
  __syncthreads();  // all K-loop LDS reads done before overwrite

#pragma unroll
  for (int j = 0; j < 4; j++) {
    int nloc = wn + j * 16 + col;
    float bb = bias[n0 + nloc];
#pragma unroll
    for (int i = 0; i < 4; i++)
#pragma unroll
      for (int r = 0; r < 4; r++) {
        int mloc = wm + i * 16 + quad * 4 + r;
        Sm[mloc * 136 + nloc] = f2h((acc[i][j][r] + bb) * oscale);
      }
  }
  __syncthreads();

  if (z != 2) {
    // q/k: [bh][s][64] -- row-contiguous 16B chunks
#pragma unroll
    for (int k = 0; k < 8; k++) {
      int c = tid + k * 256;
      int mloc = c >> 4, n = (c & 15) * 8;
      int hh = (n0 + n) >> 6, d = (n0 + n) & 63;
      half8 vv = *(const half8*)(Sm + mloc * 136 + n);
      *(half8*)(oh + ((bidx * 16 + hh) * 1024 + sbase + mloc) * 64 + d) = vv;
    }
  } else {
    // V^T: [bh][d][1024] -- transposed read, s-contiguous 16B stores
#pragma unroll
    for (int k = 0; k < 8; k++) {
      int c = tid + k * 256;
      int nloc = c & 127, s0 = (c >> 7) * 8;
      int hh = (n0 + nloc) >> 6, d = (n0 + nloc) & 63;
      u16 tmp[8];
#pragma unroll
      for (int e = 0; e < 8; e++) tmp[e] = Sm[(s0 + e) * 136 + nloc];
      *(half8*)(vth + ((bidx * 16 + hh) * 64 + d) * 1024 + sbase + s0) =
          *(half8*)tmp;
    }
    // vsum partials from fp32 acc: vsum[bh*64+d] += sum over this block's s
#pragma unroll
    for (int j = 0; j < 4; j++) {
      int nloc = wn + j * 16 + col;
      float bb = bias[n0 + nloc];
      float part = 16.0f * bb;
#pragma unroll
      for (int i = 0; i < 4; i++)
#pragma unroll
        for (int r = 0; r < 4; r++) part += acc[i][j][r];
      part += __shfl_xor(part, 16, 64);  // reduce across quads (same n)
      part += __shfl_xor(part, 32, 64);
      if (quad == 0) {
        int hh = (n0 + nloc) >> 6, d = (n0 + nloc) & 63;
        unsafeAtomicAdd(vsum + (bidx * 16 + hh) * 64 + d, part);
      }
    }
  }
}

// ---------------------------------------------------------------------------
// Swizzled tile stage for k_attn (512 threads): NC 64-row chunks of
// [rows][64] f16, global -> LDS via DMA, XOR bank swizzle on the src.
// ---------------------------------------------------------------------------
template <int NC>
__device__ __forceinline__ void stageN(u16* lds, const u16* g, int row_stride,
                                       int tid) {
#pragma unroll
  for (int p = 0; p < NC; p++) {
    int slot = (p * 512 + tid) * 8;  // element index; *2 = bytes
    int row = slot >> 6;
    int gp = (slot >> 3) & 7;
    int gl = gp ^ (row & 7);
    async_cp16(lds + slot, g + row * row_stride + gl * 8);
  }
}

// ---------------------------------------------------------------------------
// 3) flash attention, fp16, static softmax, double-buffered staging.
//    R15: QBLK=128, 512 threads (8 waves), grid 512 = 64 bh x 8 q-blocks.
//    K/V staged once per 128 q (traffic & barriers halved per unit work).
//    Wave roles: QK -> (t-block tb=w&3, q-half qh2=w>>2); PV -> q-block w.
//    Loop (R13 sync): stage t+1 (2 cp16/thread); QK 8 MFMA; mask; softmax
//    (16 exp2, 4x ds_write_b64 P); lgkmcnt(0)+s_barrier (DMA in flight);
//    PV 8 MFMA; __syncthreads.
// ---------------------------------------------------------------------------
__launch_bounds__(512)
__global__ void k_attn(const u16* __restrict__ qh_g,
                       const u16* __restrict__ kh_g,
                       const u16* __restrict__ vth_g,
                       const float* __restrict__ vsum, const int* __restrict__ elen,
                       float* __restrict__ out) {
  __shared__ u16 QP[8192];       // [128][64] swizzled: Q, then P (aliased)
  __shared__ u16 Bufs[2][8192];  // per buf: K@0 [64][64], VT@4096 [64][64]
  const int tid = threadIdx.x, l = tid & 63, w = tid >> 6;  // w in 0..7
  const int quad = l >> 4, col = l & 15;
  const int tb = w & 3;    // QK t-block
  const int qh2 = w >> 2;  // QK q-half (jq base = qh2*4)
  // ---- balance remap (bijective on [0,512)): co-resident {id, id+256}
  //      differ in batch; same-bh q-blocks are 64 apart -> same XCD ----
  const int id = blockIdx.x;
  const int b = (id + (id >> 8)) & 3;
  const int h = (id >> 2) & 15;
  const int bh = b * 16 + h;
  const int q0 = ((id >> 6) & 7) * 128;
  const int len = elen[b];

  if (q0 >= len) {  // fully-invalid tile: uniform attention over ALL t (ref)
    float val = vsum[bh * 64 + l] * (1.0f / 1024.0f);
    float* op = out + (b * 1024 + q0) * 1024 + h * 64 + l;
    for (int r = w; r < 128; r += 8) op[r * 1024] = val;
    return;
  }

  const u16* kh_b  = kh_g + bh * 65536;
  const u16* vth_b = vth_g + bh * 65536;

  // prologue: stage Q (128 rows) + tile 0, full drain
  stageN<2>(QP, qh_g + (bh * 1024 + q0) * 64, 64, tid);
  stageN<1>(Bufs[0], kh_b, 64, tid);
  stageN<1>(Bufs[0] + 4096, vth_b, 1024, tid);
  __syncthreads();

  // persistent Q as B-operand fragments: qf[jj][ks], row = (qh2*4+jj)*16+col
  half8 qf[4][2];
#pragma unroll
  for (int jj = 0; jj < 4; jj++) {
    int qrow = (qh2 * 4 + jj) * 16 + col;
#pragma unroll
    for (int ks = 0; ks < 2; ks++)
      qf[jj][ks] = *(const half8*)(QP + qrow * 64 +
                                   (((ks * 4 + quad) ^ (qrow & 7)) * 8));
  }
  __syncthreads();  // ALL Q reads done before any P write (QP aliased)

  // K A-frag offsets: row = tb*16 + col (t)
  int ko[2];
#pragma unroll
  for (int ks = 0; ks < 2; ks++) {
    int r = tb * 16 + col;
    ko[ks] = r * 64 + (((ks * 4 + quad) ^ (r & 7)) * 8);
  }
  // P A-frag offsets: row = w*16 + col (q, 0..127)
  int po[2];
#pragma unroll
  for (int ks = 0; ks < 2; ks++) {
    int r = w * 16 + col;
    po[ks] = r * 64 + (((ks * 4 + quad) ^ (r & 7)) * 8);
  }
  // V B-frag offsets (n = j*16 + col = d)
  int kvo[2][4];
#pragma unroll
  for (int ks = 0; ks < 2; ks++)
#pragma unroll
    for (int j = 0; j < 4; j++) {
      int n = j * 16 + col;
      kvo[ks][j] = n * 64 + (((ks * 4 + quad) ^ (n & 7)) * 8);
    }
  // packed P write offsets: row = (qh2*4+jj)*16+col, t-chunk = tb*2+(quad>>1)
  int p_wr[4];
  {
    int chv = tb * 2 + (quad >> 1);
#pragma unroll
    for (int jj = 0; jj < 4; jj++) {
      int row = (qh2 * 4 + jj) * 16 + col;
      p_wr[jj] = row * 64 + ((chv ^ (row & 7)) * 8) + (quad & 1) * 4;
    }
  }

  floatx4 zero4 = {0.f, 0.f, 0.f, 0.f};
  floatx4 O[4];
  float lp[4];  // per-thread l partials over this thread's t-slice
#pragma unroll
  for (int j = 0; j < 4; j++) O[j] = zero4;
#pragma unroll
  for (int jj = 0; jj < 4; jj++) lp[jj] = 0.f;

  const int ntt = (len + 63) >> 6;
  for (int tt = 0; tt < ntt; ++tt) {
    const int t0 = tt * 64;
    u16* cur = Bufs[tt & 1];
    if (tt + 1 < ntt) {  // overlap: DMA tile t+1 while computing tile t
      u16* nxt = Bufs[(tt + 1) & 1];
      const int t1 = t0 + 64;
      stageN<1>(nxt, kh_b + t1 * 64, 64, tid);
      stageN<1>(nxt + 4096, vth_b + t1, 1024, tid);
    }

    // ---- S^T = K Q (q carries 0.125*log2e); sc[jj][r]:
    //      q = (qh2*4+jj)*16 + col, t = t0 + tb*16 + quad*4 + r ----
    floatx4 sc[4];
#pragma unroll
    for (int jj = 0; jj < 4; jj++) sc[jj] = zero4;
#pragma unroll
    for (int ks = 0; ks < 2; ks++) {
      half8 kf = *(const half8*)(cur + ko[ks]);
#pragma unroll
      for (int jj = 0; jj < 4; jj++) sc[jj] = MFMA16(kf, qf[jj][ks], sc[jj]);
    }

    if (t0 + 64 > len) {  // only the last partial tile masks (t-cols >= len)
#pragma unroll
      for (int r = 0; r < 4; r++) {
        bool inv = (t0 + tb * 16 + quad * 4 + r) >= len;
#pragma unroll
        for (int jj = 0; jj < 4; jj++)
          if (inv) sc[jj][r] = -3e38f;  // exp2 -> 0 (assignment kills NaN)
      }
    }

    // ---- static softmax: p = exp2(score), f16 RTN, packed b64 writes ----
#pragma unroll
    for (int jj = 0; jj < 4; jj++) {
      float e0 = __builtin_exp2f(sc[jj][0]);
      float e1 = __builtin_exp2f(sc[jj][1]);
      float e2 = __builtin_exp2f(sc[jj][2]);
      float e3 = __builtin_exp2f(sc[jj][3]);
      lp[jj] += (e0 + e1) + (e2 + e3);
      uint2 pk;
      pk.x = (uint32_t)f2h(e0) | ((uint32_t)f2h(e1) << 16);
      pk.y = (uint32_t)f2h(e2) | ((uint32_t)f2h(e3) << 16);
      *(uint2*)(QP + p_wr[jj]) = pk;  // 4 consecutive t -> one ds_write_b64
    }

    // P handoff: waves exchange slices. lgkmcnt only -- the tile t+1 DMA
    // (vmcnt) stays in flight across this barrier.
    asm volatile("s_waitcnt lgkmcnt(0)" ::: "memory");
    __builtin_amdgcn_s_barrier();
    __builtin_amdgcn_sched_barrier(0);

    // ---- O += P * V (wave w owns q-block w) ----
#pragma unroll
    for (int ks = 0; ks < 2; ks++) {
      half8 pa = *(const half8*)(QP + po[ks]);
#pragma unroll
      for (int j = 0; j < 4; j++) {
        half8 vb = *(const half8*)(cur + 4096 + kvo[ks][j]);
        O[j] = MFMA16(pa, vb, O[j]);
      }
    }

    __syncthreads();  // drain next-tile DMA + WAR on P before next softmax
  }

  // ---- epilogue: cross-wave l reduction through (now free) Bufs ----
  float* lred = (float*)Bufs;  // [4 tb][128 q] partials
#pragma unroll
  for (int jj = 0; jj < 4; jj++) {
    float v = lp[jj];
    v += __shfl_xor(v, 16, 64);  // sum over quads (wave's 16-t slice, all tt)
    v += __shfl_xor(v, 32, 64);
    lp[jj] = v;
  }
  if (quad == 0) {
#pragma unroll
    for (int jj = 0; jj < 4; jj++)
      lred[tb * 128 + (qh2 * 4 + jj) * 16 + col] = lp[jj];
  }
  __syncthreads();

#pragma unroll
  for (int r = 0; r < 4; r++) {
    int qloc = w * 16 + quad * 4 + r;
    int s = q0 + qloc;
    float lr = (lred[qloc] + lred[128 + qloc]) +
               (lred[256 + qloc] + lred[384 + qloc]);
    float invl = 1.0f / lr;
    bool valid = (s < len);
#pragma unroll
    for (int j = 0; j < 4; j++) {
      int d = j * 16 + col;
      float val = valid ? O[j][r] * invl : vsum[bh * 64 + d] * (1.0f / 1024.0f);
      out[(b * 1024 + s) * 1024 + h * 64 + d] = val;
    }
  }
}

// ---------------------------------------------------------------------------
// launch
// ---------------------------------------------------------------------------
extern "C" void kernel_launch(void* const* d_in, const int* in_sizes, int n_in,
                              void* d_out, int out_size, void* d_ws, size_t ws_size,
                              hipStream_t stream) {
  (void)in_sizes; (void)n_in; (void)out_size; (void)ws_size;
  const float* x  = (const float*)d_in[0];
  const float* Wq = (const float*)d_in[1];
  const float* bq = (const float*)d_in[2];
  const float* Wk = (const float*)d_in[3];
  const float* bk = (const float*)d_in[4];
  const float* Wv = (const float*)d_in[5];
  const float* bv = (const float*)d_in[6];
  const int* elen = (const int*)d_in[7];
  float* out = (float*)d_out;

  char* ws = (char*)d_ws;
  const size_t MB = 1024 * 1024;
  u16* xh  = (u16*)(ws + 0 * MB);
  u16* wqT = (u16*)(ws + 8 * MB);
  u16* wkT = (u16*)(ws + 10 * MB);
  u16* wvT = (u16*)(ws + 12 * MB);
  u16* qh  = (u16*)(ws + 14 * MB);
  u16* kh  = (u16*)(ws + 22 * MB);
  u16* vth = (u16*)(ws + 30 * MB);
  float* vsum = (float*)(ws + 38 * MB);  // 4096 floats

  k_prep<<<7168, 256, 0, stream>>>(x, xh, Wq, Wk, Wv, wqT, wkT, wvT, vsum);
  k_proj<<<dim3(32, 8, 3), 256, 0, stream>>>(xh, wqT, wkT, wvT, bq, bk, bv,
                                             elen, qh, kh, vth, vsum);
  k_attn<<<512, 512, 0, stream>>>(qh, kh, vth, vsum, elen, out);
}